// Round 1
// baseline (526.182 us; speedup 1.0000x reference)
//
#include <hip/hip_runtime.h>

#define ROWS_PER_BLOCK 128
#define NUM_BASIS 67                              // GRID_SIZE + K = 64 + 3
#define TILE_FLOATS (ROWS_PER_BLOCK * NUM_BASIS)  // 8576 floats = 34304 B
#define TILE_VEC4 (TILE_FLOATS / 4)               // 2144 (divisible: 8576 % 4 == 0)

// Interior knots: knots[i] = (i-35)/32 for i in [3,67]; clamped to -1 / +1 outside.
// These values are EXACT in float32, so comparisons reproduce the reference's
// indicator semantics bit-exactly.
__device__ __forceinline__ float kv(int i) {
    i = min(max(i, 3), 67);
    return (float)(i - 35) * 0.03125f;
}

__global__ __launch_bounds__(256) void SplineBasis_kernel(const float* __restrict__ x,
                                                          float* __restrict__ out,
                                                          int B) {
    __shared__ __align__(16) float tile[TILE_FLOATS];
    const int tid = threadIdx.x;
    const int blockRow0 = blockIdx.x * ROWS_PER_BLOCK;

    // Phase 1: zero the LDS tile (the 63 zero columns per row).
    float4* t4 = (float4*)tile;
    for (int i = tid; i < TILE_VEC4; i += 256) t4[i] = make_float4(0.f, 0.f, 0.f, 0.f);
    __syncthreads();

    // Phase 2: threads 0..127 each compute one row's 4 nonzero basis values.
    if (tid < ROWS_PER_BLOCK) {
        const int row = blockRow0 + tid;
        if (row < B) {
            const float xv = x[row];
            // Reference gives an all-zero row for x < -1, x >= 1, or NaN
            // (indicator never fires). Input is uniform in [-1, 1).
            if (xv >= -1.0f && xv < 1.0f) {
                // Containing interval: knots[m] <= x < knots[m+1], m in [3,66].
                int cell = (int)floorf((xv + 1.0f) * 32.0f);
                cell = min(max(cell, 0), 63);
                int m = cell + 3;
                // Fix-up against exact knot values (handles (x+1)*32 rounding
                // at knot boundaries so we match the reference's comparisons).
                while (m > 3 && xv < kv(m)) --m;
                while (m < 66 && xv >= kv(m + 1)) ++m;

                // de Boor triangle: after degree-3 loop, N[j] = B_{m-3+j,3}(x).
                // Identical values to the reference's bottom-up DP (the
                // where(den!=0) guards in the reference only zero out terms
                // whose multiplying basis entry is already zero).
                float N[4], left[4], right[4];
                N[0] = 1.0f;
#pragma unroll
                for (int d = 1; d <= 3; ++d) {
                    left[d]  = xv - kv(m + 1 - d);
                    right[d] = kv(m + d) - xv;
                    float saved = 0.0f;
#pragma unroll
                    for (int r = 0; r < d; ++r) {
                        float temp = N[r] / (right[r + 1] + left[d - r]);
                        N[r] = saved + right[r + 1] * temp;
                        saved = left[d - r] * temp;
                    }
                    N[d] = saved;
                }

                const int c0 = tid * NUM_BASIS + (m - 3);  // m-3 in [0, 63]
                tile[c0 + 0] = N[0];
                tile[c0 + 1] = N[1];
                tile[c0 + 2] = N[2];
                tile[c0 + 3] = N[3];
            }
        }
    }
    __syncthreads();

    // Phase 3: stream the tile to global, fully coalesced float4 stores.
    // Tile base byte offset = blockIdx * 34304, which is 16B-aligned.
    const int rows = min(ROWS_PER_BLOCK, B - blockRow0);
    if (rows == ROWS_PER_BLOCK) {
        float4* o4 = (float4*)(out + (size_t)blockRow0 * NUM_BASIS);
        for (int i = tid; i < TILE_VEC4; i += 256) o4[i] = t4[i];
    } else if (rows > 0) {
        // Generic tail (not hit for B = 2,000,000: 2e6 % 128 == 0).
        const int n = rows * NUM_BASIS;
        float* o = out + (size_t)blockRow0 * NUM_BASIS;
        for (int i = tid; i < n; i += 256) o[i] = tile[i];
    }
}

extern "C" void kernel_launch(void* const* d_in, const int* in_sizes, int n_in,
                              void* d_out, int out_size, void* d_ws, size_t ws_size,
                              hipStream_t stream) {
    const float* x = (const float*)d_in[0];
    float* out = (float*)d_out;
    const int B = in_sizes[0];
    const int nblocks = (B + ROWS_PER_BLOCK - 1) / ROWS_PER_BLOCK;
    SplineBasis_kernel<<<nblocks, 256, 0, stream>>>(x, out, B);
}